// Round 8
// baseline (272.183 us; speedup 1.0000x reference)
//
#include <hip/hip_runtime.h>
#include <hip/hip_bf16.h>
#include <stdint.h>

// Problem constants
#define BT   768
#define NN   512
#define DIN  64
#define HID  128
#define EMB  16
#define SLOPE 0.01f

typedef __attribute__((ext_vector_type(8))) short bf16x8;   // 8 bf16 (4 VGPRs)
typedef __attribute__((ext_vector_type(4))) float f32x4;    // MFMA C/D frag
typedef __attribute__((ext_vector_type(4))) short short4v;

__device__ __forceinline__ short f2bf(float f) {            // fp32 -> bf16 RNE
    uint32_t u = __float_as_uint(f);
    u += 0x7fff + ((u >> 16) & 1);
    return (short)(u >> 16);
}
__device__ __forceinline__ float bf2f(short s) {
    return __uint_as_float(((uint32_t)(unsigned short)s) << 16);
}

// ---------------- workspace layout (bytes) ----------------
static const size_t OFF_PTT  = 0;           // pool_tem^T bf16 [d][o=128][i=128] = 512 KB
static const size_t OFF_PTS2 = 524288;      // P^T bf16 [d][o=128][k=64]; P[d]=W1@pool_spa[d]
static const size_t OFF_QB   = 786432;      // qb[d][o] = bp_spa[d][o] + b1@pool_spa[d], fp32 [16][128]
static const size_t OFF_H2   = 1048576;     // bf16 [n][R][o] = 100.7 MB

// ===========================================================================
// Device bodies (shared by the pipelined kernels)
// ===========================================================================

// ---- spatial: h2[n][Rbase..Rbase+384) = leaky(eb @ wcomb[n] + bcomb[n]) ----
// v6 persistent structure, 6 chunks of 64 R. smem = 35,840 shorts.
__device__ __forceinline__ void spatial_block(
    const float* __restrict__ eb, const short* __restrict__ pts2,
    const float* __restrict__ qb, const float* __restrict__ node_eb,
    short* __restrict__ h2, short* smem, int n, int Rbase)
{
    const int t = threadIdx.x;
    const int wave = t >> 6, lane = t & 63, quad = lane >> 4, l15 = lane & 15;
    const int m0 = (wave >> 1) * 32, n0 = (wave & 1) * 64;

    short* sW    = smem;             // [128][72]          9,216 shorts
    short* sEbB  = smem + 9216;      // 2 x [64][72]       9,216 shorts
    short* sOutB = smem + 18432;     // 2 x [64][136]     17,408 shorts

    const float* ebn = eb + (size_t)n * DIN;
    short* h2n = h2 + (size_t)n * (BT * HID) + (size_t)Rbase * HID;

    // issue eb chunk-0 loads first (HBM latency hides under wcomb gen)
    float4 ev[4];
    #pragma unroll
    for (int c = 0; c < 4; ++c) {
        int idx = c * 256 + t;
        int r = idx >> 4, kq = (idx & 15) * 4;
        ev[c] = *(const float4*)(ebn + (size_t)(Rbase + r) * (NN * DIN) + kq);
    }
    float ne[EMB];
    #pragma unroll
    for (int d = 0; d < EMB; ++d) ne[d] = node_eb[n * EMB + d];
    float bsr[4];
    #pragma unroll
    for (int tc = 0; tc < 4; ++tc) {
        int col = n0 + tc * 16 + l15;
        float a = 0.f;
        #pragma unroll
        for (int d = 0; d < EMB; ++d) a += ne[d] * qb[d * HID + col];
        bsr[tc] = a;
    }
    // inline wcomb: sW[o][k] = sum_d ne[d] * pts2[d][o][k]
    #pragma unroll
    for (int c = 0; c < 4; ++c) {
        int idx = c * 256 + t;
        int o = idx >> 3, k0 = (idx & 7) * 8;
        float a8[8] = {};
        #pragma unroll
        for (int d = 0; d < EMB; ++d) {
            bf16x8 pv = *(const bf16x8*)(pts2 + (size_t)d * 8192 + o * 64 + k0);
            #pragma unroll
            for (int e = 0; e < 8; ++e) a8[e] += ne[d] * bf2f(pv[e]);
        }
        bf16x8 w;
        #pragma unroll
        for (int e = 0; e < 8; ++e) w[e] = f2bf(a8[e]);
        *(bf16x8*)(sW + o * 72 + k0) = w;
    }
    // stage eb chunk 0
    #pragma unroll
    for (int c = 0; c < 4; ++c) {
        int idx = c * 256 + t;
        int r = idx >> 4, kq = (idx & 15) * 4;
        short4v s;
        s.x = f2bf(ev[c].x); s.y = f2bf(ev[c].y);
        s.z = f2bf(ev[c].z); s.w = f2bf(ev[c].w);
        *(short4v*)(sEbB + r * 72 + kq) = s;
    }
    __syncthreads();

    for (int ch = 0; ch < 6; ++ch) {
        const int cur = ch & 1;
        short* se  = sEbB + cur * 4608;
        short* snx = sEbB + (cur ^ 1) * 4608;
        short* so  = sOutB + cur * 8704;
        if (ch < 5) {                         // prefetch next chunk
            #pragma unroll
            for (int c = 0; c < 4; ++c) {
                int idx = c * 256 + t;
                int r = (ch + 1) * 64 + (idx >> 4), kq = (idx & 15) * 4;
                ev[c] = *(const float4*)(ebn + (size_t)(Rbase + r) * (NN * DIN) + kq);
            }
        }
        // GEMM: [64r x 64k] @ [64k x 128o]
        f32x4 acc[2][4] = {};
        #pragma unroll
        for (int kc = 0; kc < 2; ++kc) {
            bf16x8 a0 = *(const bf16x8*)(se + (m0 + l15) * 72 + kc * 32 + quad * 8);
            bf16x8 a1 = *(const bf16x8*)(se + (m0 + 16 + l15) * 72 + kc * 32 + quad * 8);
            #pragma unroll
            for (int tc = 0; tc < 4; ++tc) {
                bf16x8 bfr = *(const bf16x8*)(sW + (n0 + tc * 16 + l15) * 72 + kc * 32 + quad * 8);
                acc[0][tc] = __builtin_amdgcn_mfma_f32_16x16x32_bf16(a0, bfr, acc[0][tc], 0, 0, 0);
                acc[1][tc] = __builtin_amdgcn_mfma_f32_16x16x32_bf16(a1, bfr, acc[1][tc], 0, 0, 0);
            }
        }
        // epilogue into sOut[cur]
        #pragma unroll
        for (int tr = 0; tr < 2; ++tr)
            #pragma unroll
            for (int tc = 0; tc < 4; ++tc) {
                int col = n0 + tc * 16 + l15;
                #pragma unroll
                for (int r = 0; r < 4; ++r) {
                    float v = acc[tr][tc][r] + bsr[tc];
                    v = (v >= 0.f) ? v : SLOPE * v;
                    so[(m0 + tr * 16 + quad * 4 + r) * 136 + col] = f2bf(v);
                }
            }
        // stage next chunk (vmcnt wait lands here)
        if (ch < 5) {
            #pragma unroll
            for (int c = 0; c < 4; ++c) {
                int idx = c * 256 + t;
                int r = idx >> 4, kq = (idx & 15) * 4;
                short4v s;
                s.x = f2bf(ev[c].x); s.y = f2bf(ev[c].y);
                s.z = f2bf(ev[c].z); s.w = f2bf(ev[c].w);
                *(short4v*)(snx + r * 72 + kq) = s;
            }
        }
        __syncthreads();
        // contiguous 16 KB store; drains during next chunk
        #pragma unroll
        for (int c = 0; c < 4; ++c) {
            int idx = c * 256 + t;
            *(bf16x8*)(h2n + (size_t)ch * (64 * HID) + (size_t)idx * 8) =
                *(const bf16x8*)(so + (idx >> 4) * 136 + (idx & 15) * 8);
        }
    }
}

// ---- temporal: out[R][nt*64..] for 4 n-chunks starting at ntBase ----
// smem usage: 26,112 shorts (sWt 17,408 + sH2 8,704).
__device__ __forceinline__ void temporal_block(
    const short* __restrict__ h2, const short* __restrict__ ptt,
    const float* __restrict__ bp_tem, const float* __restrict__ time_eb,
    const float* __restrict__ W3, const float* __restrict__ b3,
    float* __restrict__ out, short* smem, int R, int ntBase)
{
    const int t = threadIdx.x;
    const int wave = t >> 6, lane = t & 63, quad = lane >> 4, l15 = lane & 15;
    const int m0 = wave * 16;
    short* sWt = smem;               // [128][136]
    short* sH2 = smem + 17408;       // [64][136]
    const short* hb = h2 + (size_t)R * HID;

    // issue chunk-0 h2 loads first (latency hides under wtem gen)
    bf16x8 hreg[4];
    #pragma unroll
    for (int c = 0; c < 4; ++c) {
        int idx = c * 256 + t;
        hreg[c] = *(const bf16x8*)(hb + (size_t)(ntBase * 64 + (idx >> 4)) * (BT * HID) + (idx & 15) * 8);
    }
    float te[EMB];
    #pragma unroll
    for (int d = 0; d < EMB; ++d) te[d] = time_eb[R * EMB + d];
    // inline wtem: sWt[o][i] = sum_d te[d] * ptt[d][o][i]
    #pragma unroll
    for (int c = 0; c < 8; ++c) {
        int idx = c * 256 + t;
        int o = idx >> 4, i0 = (idx & 15) * 8;
        float a8[8] = {};
        #pragma unroll
        for (int d = 0; d < EMB; ++d) {
            bf16x8 pv = *(const bf16x8*)(ptt + (size_t)d * 16384 + o * 128 + i0);
            #pragma unroll
            for (int e = 0; e < 8; ++e) a8[e] += te[d] * bf2f(pv[e]);
        }
        bf16x8 w;
        #pragma unroll
        for (int e = 0; e < 8; ++e) w[e] = f2bf(a8[e]);
        *(bf16x8*)(sWt + o * 136 + i0) = w;
    }
    float btr[8], w3r0[8], w3r1[8];
    #pragma unroll
    for (int tc = 0; tc < 8; ++tc) {
        int o = tc * 16 + l15;
        float a = 0.f;
        #pragma unroll
        for (int d = 0; d < EMB; ++d) a += te[d] * bp_tem[d * HID + o];
        btr[tc] = a;
        w3r0[tc] = W3[2 * o]; w3r1[tc] = W3[2 * o + 1];
    }
    const float b30 = b3[0], b31 = b3[1];

    #pragma unroll
    for (int c = 0; c < 4; ++c) {
        int idx = c * 256 + t;
        *(bf16x8*)(sH2 + (idx >> 4) * 136 + (idx & 15) * 8) = hreg[c];
    }
    __syncthreads();

    for (int j = 0; j < 4; ++j) {
        const int nt = ntBase + j;
        if (j < 3) {
            #pragma unroll
            for (int c = 0; c < 4; ++c) {
                int idx = c * 256 + t;
                hreg[c] = *(const bf16x8*)(hb + (size_t)((nt + 1) * 64 + (idx >> 4)) * (BT * HID) + (idx & 15) * 8);
            }
        }
        f32x4 acc[8] = {};
        #pragma unroll
        for (int kc = 0; kc < 4; ++kc) {
            bf16x8 a = *(const bf16x8*)(sH2 + (m0 + l15) * 136 + kc * 32 + quad * 8);
            #pragma unroll
            for (int tc = 0; tc < 8; ++tc) {
                bf16x8 b = *(const bf16x8*)(sWt + (tc * 16 + l15) * 136 + kc * 32 + quad * 8);
                acc[tc] = __builtin_amdgcn_mfma_f32_16x16x32_bf16(a, b, acc[tc], 0, 0, 0);
            }
        }
        float pl[4][2] = {};
        #pragma unroll
        for (int tc = 0; tc < 8; ++tc) {
            #pragma unroll
            for (int r = 0; r < 4; ++r) {
                float v = acc[tc][r] + btr[tc];
                v = (v >= 0.f) ? v : SLOPE * v;
                pl[r][0] += v * w3r0[tc];
                pl[r][1] += v * w3r1[tc];
            }
        }
        #pragma unroll
        for (int m = 1; m <= 8; m <<= 1)
            #pragma unroll
            for (int r = 0; r < 4; ++r) {
                pl[r][0] += __shfl_xor(pl[r][0], m);
                pl[r][1] += __shfl_xor(pl[r][1], m);
            }
        if (l15 == 0) {
            #pragma unroll
            for (int r = 0; r < 4; ++r) {
                int nrow = nt * 64 + m0 + quad * 4 + r;
                *(float2*)(out + ((size_t)R * NN + nrow) * 2) =
                    make_float2(pl[r][0] + b30, pl[r][1] + b31);
            }
        }
        __syncthreads();
        if (j < 3) {
            #pragma unroll
            for (int c = 0; c < 4; ++c) {
                int idx = c * 256 + t;
                *(bf16x8*)(sH2 + (idx >> 4) * 136 + (idx & 15) * 8) = hreg[c];
            }
            __syncthreads();
        }
    }
}

// ---- ptt transpose block (moved out of k_prep into k_sA) ----
__device__ __forceinline__ void ptt_block(const float* __restrict__ pool_tem,
                                          short* __restrict__ ptt,
                                          short* s, int bb)
{
    const int t = threadIdx.x;
    const int d = bb >> 2, o0 = (bb & 3) * 32;
    #pragma unroll
    for (int c = 0; c < 16; ++c) {
        int e = c * 256 + t;
        int i = e >> 5, oo = e & 31;
        s[oo * 136 + i] = f2bf(pool_tem[(d * HID + i) * HID + o0 + oo]);
    }
    __syncthreads();
    #pragma unroll
    for (int c = 0; c < 8; ++c) {
        int e = c * 256 + t;
        int oo = e >> 6, ii = (e & 63) * 2;
        uint32_t lo = (unsigned short)s[oo * 136 + ii];
        uint32_t hi = (unsigned short)s[oo * 136 + ii + 1];
        ((uint32_t*)ptt)[((d * HID + o0 + oo) * HID + ii) >> 1] = lo | (hi << 16);
    }
}

// ===========================================================================
// Kernels
// ===========================================================================

// k_prep (18 blocks): b 0..1 qb table; b 2..17 pts2 (MFMA fold of W1).
__global__ __launch_bounds__(256)
void k_prep(const float* __restrict__ pool_spa, const float* __restrict__ W1,
            const float* __restrict__ b1, const float* __restrict__ bp_spa,
            short* __restrict__ pts2, float* __restrict__ qb)
{
    const int b = blockIdx.x, t = threadIdx.x;
    __shared__ short smem[26112];

    if (b < 2) {                             // ---- qb table ----
        const int dbase = b * 8;
        if (t < 128) {
            float a[8];
            #pragma unroll
            for (int dd = 0; dd < 8; ++dd) a[dd] = bp_spa[(dbase + dd) * HID + t];
            for (int i = 0; i < HID; ++i) {
                float bv = b1[i];
                #pragma unroll
                for (int dd = 0; dd < 8; ++dd)
                    a[dd] += bv * pool_spa[((dbase + dd) * HID + i) * HID + t];
            }
            #pragma unroll
            for (int dd = 0; dd < 8; ++dd) qb[(dbase + dd) * HID + t] = a[dd];
        }
        return;
    }
    // ---- pts2: P^T[d] = (pool_spa[d]^T @ W1^T), out [o=128][k=64]
    {
        const int d = b - 2;
        const int wave = t >> 6, lane = t & 63, quad = lane >> 4, l15 = lane & 15;
        const int m0 = wave * 32;
        short* sPT  = smem;                  // [128][136]
        short* sW1b = smem + 128 * 136;      // [64][136] -- NOTE: exceeds 26112? no: 17408+8704=26112 OK
        #pragma unroll
        for (int c = 0; c < 64; ++c) {
            int idx = c * 256 + t;
            int i = idx >> 7, o = idx & 127;
            sPT[o * 136 + i] = f2bf(pool_spa[(d * HID + i) * HID + o]);
        }
        #pragma unroll
        for (int c = 0; c < 32; ++c) {
            int idx = c * 256 + t;           // W1 is [k=64][i=128] row-major
            sW1b[(idx >> 7) * 136 + (idx & 127)] = f2bf(W1[idx]);
        }
        __syncthreads();
        f32x4 acc[2][4] = {};
        #pragma unroll
        for (int kc = 0; kc < 4; ++kc) {
            bf16x8 a0 = *(const bf16x8*)(sPT + (m0 + l15) * 136 + kc * 32 + quad * 8);
            bf16x8 a1 = *(const bf16x8*)(sPT + (m0 + 16 + l15) * 136 + kc * 32 + quad * 8);
            #pragma unroll
            for (int tc = 0; tc < 4; ++tc) {
                bf16x8 bb = *(const bf16x8*)(sW1b + (tc * 16 + l15) * 136 + kc * 32 + quad * 8);
                acc[0][tc] = __builtin_amdgcn_mfma_f32_16x16x32_bf16(a0, bb, acc[0][tc], 0, 0, 0);
                acc[1][tc] = __builtin_amdgcn_mfma_f32_16x16x32_bf16(a1, bb, acc[1][tc], 0, 0, 0);
            }
        }
        __syncthreads();
        short* sO = smem;                    // reuse: [128][72]
        #pragma unroll
        for (int tr = 0; tr < 2; ++tr)
            #pragma unroll
            for (int tc = 0; tc < 4; ++tc)
                #pragma unroll
                for (int r = 0; r < 4; ++r)
                    sO[(m0 + tr * 16 + quad * 4 + r) * 72 + tc * 16 + l15] = f2bf(acc[tr][tc][r]);
        __syncthreads();
        #pragma unroll
        for (int c = 0; c < 4; ++c) {
            int idx = c * 256 + t;
            int row = idx >> 3, ko = (idx & 7) * 8;
            *(bf16x8*)(pts2 + (size_t)d * 8192 + row * 64 + ko) =
                *(const bf16x8*)(sO + row * 72 + ko);
        }
    }
}

// k_sA (576 blocks): b 0..63 ptt transpose; b 64..575 spatial n in [0,256).
__global__ __launch_bounds__(256)
void k_sA(const float* __restrict__ eb, const short* __restrict__ pts2,
          const float* __restrict__ qb, const float* __restrict__ node_eb,
          const float* __restrict__ pool_tem, short* __restrict__ ptt,
          short* __restrict__ h2)
{
    __shared__ short smem[35840];            // 71,680 B -> 2 blocks/CU
    const int b = blockIdx.x;
    if (b < 64) { ptt_block(pool_tem, ptt, smem, b); return; }
    const int sb = b - 64;
    spatial_block(eb, pts2, qb, node_eb, h2, smem, sb >> 1, (sb & 1) * 384);
}

// k_mix (1280 blocks, 2:3 interleave): 512 spatial (n 256..511) + 768
// temporal (all R, n-chunks 0..3). Spatial writes h2[n>=256] while temporal
// reads h2[n<256] (produced by k_sA) -- disjoint, no race. Co-resident
// roles fill each other's memory-latency gaps.
__global__ __launch_bounds__(256)
void k_mix(const float* __restrict__ eb, const short* __restrict__ pts2,
           const float* __restrict__ qb, const float* __restrict__ node_eb,
           short* __restrict__ h2, const short* __restrict__ ptt,
           const float* __restrict__ bp_tem, const float* __restrict__ time_eb,
           const float* __restrict__ W3, const float* __restrict__ b3,
           float* __restrict__ out)
{
    __shared__ short smem[35840];            // union; 2 blocks/CU
    const int b = blockIdx.x;
    const int g = b / 5, r = b % 5;          // 256 groups of {2 spatial, 3 temporal}
    if (r < 2) {
        const int sb = g * 2 + r;            // 0..511
        spatial_block(eb, pts2, qb, node_eb, h2, smem, 256 + (sb >> 1), (sb & 1) * 384);
    } else {
        const int R = g * 3 + (r - 2);       // 0..767
        temporal_block(h2, ptt, bp_tem, time_eb, W3, b3, out, smem, R, 0);
    }
}

// k_tB (768 blocks): temporal n-chunks 4..7. Own 52 KB LDS -> 3 blocks/CU.
__global__ __launch_bounds__(256, 3)
void k_tB(const short* __restrict__ h2, const short* __restrict__ ptt,
          const float* __restrict__ bp_tem, const float* __restrict__ time_eb,
          const float* __restrict__ W3, const float* __restrict__ b3,
          float* __restrict__ out)
{
    __shared__ short smem[26112];
    temporal_block(h2, ptt, bp_tem, time_eb, W3, b3, out, smem, blockIdx.x, 4);
}

extern "C" void kernel_launch(void* const* d_in, const int* in_sizes, int n_in,
                              void* d_out, int out_size, void* d_ws, size_t ws_size,
                              hipStream_t stream) {
    const float* eb        = (const float*)d_in[0];
    const float* time_eb   = (const float*)d_in[1];
    const float* node_eb   = (const float*)d_in[2];
    const float* W1        = (const float*)d_in[3];
    const float* b1        = (const float*)d_in[4];
    const float* W3        = (const float*)d_in[5];
    const float* b3        = (const float*)d_in[6];
    const float* pool_spa  = (const float*)d_in[7];
    const float* bpool_spa = (const float*)d_in[8];
    const float* pool_tem  = (const float*)d_in[9];
    const float* bpool_tem = (const float*)d_in[10];
    float* out = (float*)d_out;

    char* ws = (char*)d_ws;
    short* ptt  = (short*)(ws + OFF_PTT);
    short* pts2 = (short*)(ws + OFF_PTS2);
    float* qb   = (float*)(ws + OFF_QB);
    short* h2   = (short*)(ws + OFF_H2);

    k_prep<<<18, 256, 0, stream>>>(pool_spa, W1, b1, bpool_spa, pts2, qb);
    k_sA<<<576, 256, 0, stream>>>(eb, pts2, qb, node_eb, pool_tem, ptt, h2);
    k_mix<<<1280, 256, 0, stream>>>(eb, pts2, qb, node_eb, h2, ptt, bpool_tem,
                                    time_eb, W3, b3, out);
    k_tB<<<768, 256, 0, stream>>>(h2, ptt, bpool_tem, time_eb, W3, b3, out);
}

// Round 9
// 246.438 us; speedup vs baseline: 1.1045x; 1.1045x over previous
//
#include <hip/hip_runtime.h>
#include <hip/hip_bf16.h>
#include <stdint.h>

// Problem constants
#define BT   768
#define NN   512
#define DIN  64
#define HID  128
#define EMB  16
#define SLOPE 0.01f

typedef __attribute__((ext_vector_type(8))) short bf16x8;   // 8 bf16 (4 VGPRs)
typedef __attribute__((ext_vector_type(4))) float f32x4;    // MFMA C/D frag
typedef __attribute__((ext_vector_type(4))) short short4v;

__device__ __forceinline__ short f2bf(float f) {            // fp32 -> bf16 RNE
    uint32_t u = __float_as_uint(f);
    u += 0x7fff + ((u >> 16) & 1);
    return (short)(u >> 16);
}
__device__ __forceinline__ float bf2f(short s) {
    return __uint_as_float(((uint32_t)(unsigned short)s) << 16);
}

// ---------------- workspace layout (bytes) ----------------
// Hypernetwork weights are NEVER materialized: consumers combine the tiny
// (L2-resident) pool tensors inline. h2 is [R][n][o] (R-major): k_temporal
// (the READER) gets fully sequential 192 KB streams; k_spatial's strided
// writes were measured layout-insensitive (v3 vs v4 A/B, both 62 us).
static const size_t OFF_PTT  = 0;           // pool_tem^T bf16 [d][o=128][i=128] = 512 KB
static const size_t OFF_PTS2 = 524288;      // P^T bf16 [d][o=128][k=64]; P[d]=W1@pool_spa[d]
static const size_t OFF_QB   = 786432;      // qb[d][o] = bp_spa[d][o] + b1@pool_spa[d], fp32 [16][128]
static const size_t OFF_H2   = 1048576;     // bf16 [R][n][o] = 100.7 MB

// ---------------------------------------------------------------------------
// k_prep (82 blocks):
//   b 0..63  : transpose pool_tem -> ptt bf16 [d][o][i]
//   b 64..65 : qb[d][o] = bp_spa[d][o] + sum_i b1[i]*pool_spa[d][i][o]
//   b 66..81 : pts2: P^T[d][o][k] = sum_i pool_spa[d][i][o]*W1[k][i]  (MFMA)
// ---------------------------------------------------------------------------
__global__ __launch_bounds__(256)
void k_prep(const float* __restrict__ pool_spa, const float* __restrict__ pool_tem,
            const float* __restrict__ W1, const float* __restrict__ b1,
            const float* __restrict__ bp_spa,
            short* __restrict__ ptt, short* __restrict__ pts2,
            float* __restrict__ qb)
{
    const int b = blockIdx.x, t = threadIdx.x;
    __shared__ short smem[26112];            // 52.2 KB max (pts2 branch)

    if (b < 64) {                            // ---- pool_tem transpose ----
        const int d = b >> 2, o0 = (b & 3) * 32;
        short* s = smem;                     // [32][136]
        #pragma unroll
        for (int c = 0; c < 16; ++c) {
            int e = c * 256 + t;
            int i = e >> 5, oo = e & 31;
            s[oo * 136 + i] = f2bf(pool_tem[(d * HID + i) * HID + o0 + oo]);
        }
        __syncthreads();
        #pragma unroll
        for (int c = 0; c < 8; ++c) {
            int e = c * 256 + t;
            int oo = e >> 6, ii = (e & 63) * 2;
            uint32_t lo = (unsigned short)s[oo * 136 + ii];
            uint32_t hi = (unsigned short)s[oo * 136 + ii + 1];
            ((uint32_t*)ptt)[((d * HID + o0 + oo) * HID + ii) >> 1] = lo | (hi << 16);
        }
        return;
    }
    if (b < 66) {                            // ---- qb table ----
        const int dbase = (b - 64) * 8;
        if (t < 128) {
            float a[8];
            #pragma unroll
            for (int dd = 0; dd < 8; ++dd) a[dd] = bp_spa[(dbase + dd) * HID + t];
            for (int i = 0; i < HID; ++i) {
                float bv = b1[i];
                #pragma unroll
                for (int dd = 0; dd < 8; ++dd)
                    a[dd] += bv * pool_spa[((dbase + dd) * HID + i) * HID + t];
            }
            #pragma unroll
            for (int dd = 0; dd < 8; ++dd) qb[(dbase + dd) * HID + t] = a[dd];
        }
        return;
    }
    // ---- pts2: P^T[d] = (pool_spa[d]^T @ W1^T), out [o=128][k=64], contraction i=128
    {
        const int d = b - 66;
        const int wave = t >> 6, lane = t & 63, quad = lane >> 4, l15 = lane & 15;
        const int m0 = wave * 32;
        short* sPT  = smem;                  // [128][136] pool^T bf16 [o][i]
        short* sW1b = smem + 128 * 136;      // [64][136]  W1 bf16 [k][i]
        #pragma unroll
        for (int c = 0; c < 64; ++c) {
            int idx = c * 256 + t;
            int i = idx >> 7, o = idx & 127;
            sPT[o * 136 + i] = f2bf(pool_spa[(d * HID + i) * HID + o]);
        }
        #pragma unroll
        for (int c = 0; c < 32; ++c) {
            int idx = c * 256 + t;           // W1 is [k=64][i=128] row-major
            sW1b[(idx >> 7) * 136 + (idx & 127)] = f2bf(W1[idx]);
        }
        __syncthreads();
        f32x4 acc[2][4] = {};
        #pragma unroll
        for (int kc = 0; kc < 4; ++kc) {
            bf16x8 a0 = *(const bf16x8*)(sPT + (m0 + l15) * 136 + kc * 32 + quad * 8);
            bf16x8 a1 = *(const bf16x8*)(sPT + (m0 + 16 + l15) * 136 + kc * 32 + quad * 8);
            #pragma unroll
            for (int tc = 0; tc < 4; ++tc) {
                bf16x8 bb = *(const bf16x8*)(sW1b + (tc * 16 + l15) * 136 + kc * 32 + quad * 8);
                acc[0][tc] = __builtin_amdgcn_mfma_f32_16x16x32_bf16(a0, bb, acc[0][tc], 0, 0, 0);
                acc[1][tc] = __builtin_amdgcn_mfma_f32_16x16x32_bf16(a1, bb, acc[1][tc], 0, 0, 0);
            }
        }
        __syncthreads();
        short* sO = smem;                    // reuse: [128][72]
        #pragma unroll
        for (int tr = 0; tr < 2; ++tr)
            #pragma unroll
            for (int tc = 0; tc < 4; ++tc)
                #pragma unroll
                for (int r = 0; r < 4; ++r)
                    sO[(m0 + tr * 16 + quad * 4 + r) * 72 + tc * 16 + l15] = f2bf(acc[tr][tc][r]);
        __syncthreads();
        #pragma unroll
        for (int c = 0; c < 4; ++c) {
            int idx = c * 256 + t;
            int row = idx >> 3, ko = (idx & 7) * 8;
            *(bf16x8*)(pts2 + (size_t)d * 8192 + row * 64 + ko) =
                *(const bf16x8*)(sO + row * 72 + ko);
        }
    }
}

// ---------------------------------------------------------------------------
// k_spatial (round-6 v6 structure, h2 now [R][n][o]): persistent per-n block,
// wcomb generated inline from pts2 (L2-hot), bias from qb. 12 chunks of 64 R,
// eb + sOut double-buffered, 2 barriers/chunk. Stores are 256 B segments at
// 128 KB stride -- measured layout-insensitive for this kernel (v3 vs v4).
// LDS 71,680 B -> 2 blocks/CU (grid 512 = exactly 2/CU).
// ---------------------------------------------------------------------------
__global__ __launch_bounds__(256)
void k_spatial(const float* __restrict__ eb, const short* __restrict__ pts2,
               const float* __restrict__ qb, const float* __restrict__ node_eb,
               short* __restrict__ h2)
{
    const int n = blockIdx.x;
    const int t = threadIdx.x;
    const int wave = t >> 6, lane = t & 63, quad = lane >> 4, l15 = lane & 15;
    const int m0 = (wave >> 1) * 32, n0 = (wave & 1) * 64;

    __shared__ short sW[128 * 72];       // wcomb[n] as [o][k]   18,432 B
    __shared__ short sEb[2][64 * 72];    // eb chunk, dbuf       18,432 B
    __shared__ short sOut[2][64 * 136];  // output staging, dbuf 34,816 B

    const float* ebn = eb + (size_t)n * DIN;          // + r*NN*DIN walks rows
    short* h2n = h2 + (size_t)n * HID;                // [R][n][o]: + R*NN*HID walks R

    // ---- issue eb chunk-0 loads first (HBM latency hides under wcomb gen) ----
    float4 ev[4];
    #pragma unroll
    for (int c = 0; c < 4; ++c) {
        int idx = c * 256 + t;
        int r = idx >> 4, kq = (idx & 15) * 4;
        ev[c] = *(const float4*)(ebn + (size_t)r * (NN * DIN) + kq);
    }
    // ---- node embedding (uniform across block) ----
    float ne[EMB];
    #pragma unroll
    for (int d = 0; d < EMB; ++d) ne[d] = node_eb[n * EMB + d];
    // ---- combined bias: bsr = sum_d ne[d] * qb[d][col] ----
    float bsr[4];
    #pragma unroll
    for (int tc = 0; tc < 4; ++tc) {
        int col = n0 + tc * 16 + l15;
        float a = 0.f;
        #pragma unroll
        for (int d = 0; d < EMB; ++d) a += ne[d] * qb[d * HID + col];
        bsr[tc] = a;
    }
    // ---- inline wcomb: sW[o][k] = sum_d ne[d] * pts2[d][o][k] ----
    #pragma unroll
    for (int c = 0; c < 4; ++c) {
        int idx = c * 256 + t;
        int o = idx >> 3, k0 = (idx & 7) * 8;
        float a8[8] = {};
        #pragma unroll
        for (int d = 0; d < EMB; ++d) {
            bf16x8 pv = *(const bf16x8*)(pts2 + (size_t)d * 8192 + o * 64 + k0);
            #pragma unroll
            for (int e = 0; e < 8; ++e) a8[e] += ne[d] * bf2f(pv[e]);
        }
        bf16x8 w;
        #pragma unroll
        for (int e = 0; e < 8; ++e) w[e] = f2bf(a8[e]);
        *(bf16x8*)(sW + o * 72 + k0) = w;
    }
    // ---- stage eb chunk 0 ----
    #pragma unroll
    for (int c = 0; c < 4; ++c) {
        int idx = c * 256 + t;
        int r = idx >> 4, kq = (idx & 15) * 4;
        short4v s;
        s.x = f2bf(ev[c].x); s.y = f2bf(ev[c].y);
        s.z = f2bf(ev[c].z); s.w = f2bf(ev[c].w);
        *(short4v*)(sEb[0] + r * 72 + kq) = s;
    }
    __syncthreads();

    // ---- main loop over 12 R-chunks of 64 rows ----
    for (int ch = 0; ch < 12; ++ch) {
        const int cur = ch & 1, nxt = cur ^ 1;
        // issue next chunk's global loads (latency hidden under MFMA+epilogue)
        if (ch < 11) {
            #pragma unroll
            for (int c = 0; c < 4; ++c) {
                int idx = c * 256 + t;
                int r = (ch + 1) * 64 + (idx >> 4), kq = (idx & 15) * 4;
                ev[c] = *(const float4*)(ebn + (size_t)r * (NN * DIN) + kq);
            }
        }
        // GEMM: [64r x 64k] @ [64k x 128o]
        f32x4 acc[2][4] = {};
        #pragma unroll
        for (int kc = 0; kc < 2; ++kc) {
            bf16x8 a0 = *(const bf16x8*)(sEb[cur] + (m0 + l15) * 72 + kc * 32 + quad * 8);
            bf16x8 a1 = *(const bf16x8*)(sEb[cur] + (m0 + 16 + l15) * 72 + kc * 32 + quad * 8);
            #pragma unroll
            for (int tc = 0; tc < 4; ++tc) {
                bf16x8 bfr = *(const bf16x8*)(sW + (n0 + tc * 16 + l15) * 72 + kc * 32 + quad * 8);
                acc[0][tc] = __builtin_amdgcn_mfma_f32_16x16x32_bf16(a0, bfr, acc[0][tc], 0, 0, 0);
                acc[1][tc] = __builtin_amdgcn_mfma_f32_16x16x32_bf16(a1, bfr, acc[1][tc], 0, 0, 0);
            }
        }
        // epilogue into sOut[cur]
        #pragma unroll
        for (int tr = 0; tr < 2; ++tr)
            #pragma unroll
            for (int tc = 0; tc < 4; ++tc) {
                int col = n0 + tc * 16 + l15;
                #pragma unroll
                for (int r = 0; r < 4; ++r) {
                    float v = acc[tr][tc][r] + bsr[tc];
                    v = (v >= 0.f) ? v : SLOPE * v;
                    sOut[cur][(m0 + tr * 16 + quad * 4 + r) * 136 + col] = f2bf(v);
                }
            }
        // stage next chunk into the other eb buffer (vmcnt wait lands here)
        if (ch < 11) {
            #pragma unroll
            for (int c = 0; c < 4; ++c) {
                int idx = c * 256 + t;
                int r = idx >> 4, kq = (idx & 15) * 4;
                short4v s;
                s.x = f2bf(ev[c].x); s.y = f2bf(ev[c].y);
                s.z = f2bf(ev[c].z); s.w = f2bf(ev[c].w);
                *(short4v*)(sEb[nxt] + r * 72 + kq) = s;
            }
        }
        __syncthreads();                 // sOut[cur] + sEb[nxt] visible
        // store chunk to h2[R][n][o]; drains during next chunk's compute
        #pragma unroll
        for (int c = 0; c < 4; ++c) {
            int idx = c * 256 + t;
            int row = idx >> 4, col8 = (idx & 15) * 8;
            *(bf16x8*)(h2n + (size_t)(ch * 64 + row) * (NN * HID) + col8) =
                *(const bf16x8*)(sOut[cur] + row * 136 + col8);
        }
    }
}

// ---------------------------------------------------------------------------
// k_temporal (round-6 v2 structure, h2 now [R][n][o]): persistent per-R,
// wtem/btem generated inline from ptt/bp_tem. h2 reads are now FULLY
// SEQUENTIAL: block R streams h2[R][0..512][128] = 192 KB contiguous
// (16 KB per chunk), L3-resident. LDS 52,224 B -> 3 blocks/CU.
// ---------------------------------------------------------------------------
__global__ __launch_bounds__(256, 3)
void k_temporal(const short* __restrict__ h2, const short* __restrict__ ptt,
                const float* __restrict__ bp_tem, const float* __restrict__ time_eb,
                const float* __restrict__ W3, const float* __restrict__ b3,
                float* __restrict__ out)
{
    const int R = blockIdx.x;
    const int t = threadIdx.x;
    const int wave = t >> 6, lane = t & 63, quad = lane >> 4, l15 = lane & 15;
    const int m0 = wave * 16;

    __shared__ short sWt[128 * 136];     // 34,816 B
    __shared__ short sH2[64 * 136];      // 17,408 B

    const short* hb = h2 + (size_t)R * (NN * HID);    // [R][n][o]: contiguous

    // ---- issue chunk-0 h2 loads first (latency hides under wtem gen) ----
    bf16x8 hreg[4];
    #pragma unroll
    for (int c = 0; c < 4; ++c) {
        int idx = c * 256 + t;
        hreg[c] = *(const bf16x8*)(hb + (size_t)idx * 8);
    }
    // ---- time embedding (uniform across block) ----
    float te[EMB];
    #pragma unroll
    for (int d = 0; d < EMB; ++d) te[d] = time_eb[R * EMB + d];
    // ---- inline wtem: sWt[o][i] = sum_d te[d] * ptt[d][o][i] ----
    #pragma unroll
    for (int c = 0; c < 8; ++c) {
        int idx = c * 256 + t;
        int o = idx >> 4, i0 = (idx & 15) * 8;
        float a8[8] = {};
        #pragma unroll
        for (int d = 0; d < EMB; ++d) {
            bf16x8 pv = *(const bf16x8*)(ptt + (size_t)d * 16384 + o * 128 + i0);
            #pragma unroll
            for (int e = 0; e < 8; ++e) a8[e] += te[d] * bf2f(pv[e]);
        }
        bf16x8 w;
        #pragma unroll
        for (int e = 0; e < 8; ++e) w[e] = f2bf(a8[e]);
        *(bf16x8*)(sWt + o * 136 + i0) = w;
    }
    // ---- inline btem + W3 registers ----
    float btr[8], w3r0[8], w3r1[8];
    #pragma unroll
    for (int tc = 0; tc < 8; ++tc) {
        int o = tc * 16 + l15;
        float a = 0.f;
        #pragma unroll
        for (int d = 0; d < EMB; ++d) a += te[d] * bp_tem[d * HID + o];
        btr[tc] = a;
        w3r0[tc] = W3[2 * o]; w3r1[tc] = W3[2 * o + 1];
    }
    const float b30 = b3[0], b31 = b3[1];

    // ---- stage chunk 0 ----
    #pragma unroll
    for (int c = 0; c < 4; ++c) {
        int idx = c * 256 + t;
        *(bf16x8*)(sH2 + (idx >> 4) * 136 + (idx & 15) * 8) = hreg[c];
    }
    __syncthreads();

    // ---- loop over 8 n-chunks of 64 (sequential 16 KB reads) ----
    for (int nt = 0; nt < 8; ++nt) {
        if (nt < 7) {
            #pragma unroll
            for (int c = 0; c < 4; ++c) {
                int idx = c * 256 + t;
                hreg[c] = *(const bf16x8*)(hb + (size_t)((nt + 1) * 1024 + idx) * 8);
            }
        }
        f32x4 acc[8] = {};
        #pragma unroll
        for (int kc = 0; kc < 4; ++kc) {
            bf16x8 a = *(const bf16x8*)(sH2 + (m0 + l15) * 136 + kc * 32 + quad * 8);
            #pragma unroll
            for (int tc = 0; tc < 8; ++tc) {
                bf16x8 b = *(const bf16x8*)(sWt + (tc * 16 + l15) * 136 + kc * 32 + quad * 8);
                acc[tc] = __builtin_amdgcn_mfma_f32_16x16x32_bf16(a, b, acc[tc], 0, 0, 0);
            }
        }
        float pl[4][2] = {};
        #pragma unroll
        for (int tc = 0; tc < 8; ++tc) {
            #pragma unroll
            for (int r = 0; r < 4; ++r) {
                float v = acc[tc][r] + btr[tc];
                v = (v >= 0.f) ? v : SLOPE * v;
                pl[r][0] += v * w3r0[tc];
                pl[r][1] += v * w3r1[tc];
            }
        }
        #pragma unroll
        for (int m = 1; m <= 8; m <<= 1)
            #pragma unroll
            for (int r = 0; r < 4; ++r) {
                pl[r][0] += __shfl_xor(pl[r][0], m);
                pl[r][1] += __shfl_xor(pl[r][1], m);
            }
        if (l15 == 0) {
            #pragma unroll
            for (int r = 0; r < 4; ++r) {
                int nrow = nt * 64 + m0 + quad * 4 + r;
                *(float2*)(out + ((size_t)R * NN + nrow) * 2) =
                    make_float2(pl[r][0] + b30, pl[r][1] + b31);
            }
        }
        __syncthreads();                 // sH2 reads done
        if (nt < 7) {
            #pragma unroll
            for (int c = 0; c < 4; ++c) {
                int idx = c * 256 + t;
                *(bf16x8*)(sH2 + (idx >> 4) * 136 + (idx & 15) * 8) = hreg[c];
            }
            __syncthreads();
        }
    }
}

extern "C" void kernel_launch(void* const* d_in, const int* in_sizes, int n_in,
                              void* d_out, int out_size, void* d_ws, size_t ws_size,
                              hipStream_t stream) {
    const float* eb        = (const float*)d_in[0];
    const float* time_eb   = (const float*)d_in[1];
    const float* node_eb   = (const float*)d_in[2];
    const float* W1        = (const float*)d_in[3];
    const float* b1        = (const float*)d_in[4];
    const float* W3        = (const float*)d_in[5];
    const float* b3        = (const float*)d_in[6];
    const float* pool_spa  = (const float*)d_in[7];
    const float* bpool_spa = (const float*)d_in[8];
    const float* pool_tem  = (const float*)d_in[9];
    const float* bpool_tem = (const float*)d_in[10];
    float* out = (float*)d_out;

    char* ws = (char*)d_ws;
    short* ptt  = (short*)(ws + OFF_PTT);
    short* pts2 = (short*)(ws + OFF_PTS2);
    float* qb   = (float*)(ws + OFF_QB);
    short* h2   = (short*)(ws + OFF_H2);

    k_prep<<<82, 256, 0, stream>>>(pool_spa, pool_tem, W1, b1, bpool_spa,
                                   ptt, pts2, qb);
    k_spatial<<<dim3(NN), 256, 0, stream>>>(eb, pts2, qb, node_eb, h2);
    k_temporal<<<dim3(BT), 256, 0, stream>>>(h2, ptt, bpool_tem, time_eb, W3, b3, out);
}